// Round 17
// baseline (104.108 us; speedup 1.0000x reference)
//
#include <hip/hip_runtime.h>
#include <hip/hip_bf16.h>

// RGCN CSR, two layers, MI355X.  Transform-then-gather, separate kernels.
//   xw1[n][512B] = int8(x @ W1flat, scale 16)   <- k_xw1 (bf16 MFMA, int8 out)
//   h[n][64]     = relu(gather_int8(xw1))/16    <- k_gs_relu (exact int accum)
//   xw2[n][320]  = h @ W2flat (bf16)            <- k_xw2
//   out[n][40]   = log_softmax(gather(xw2))     <- k_gs_lsm
// R17 = R15 VERBATIM (best stable: 103.8us, absmax 1.5, replay-stable).
// R16's two-phase LDS staging gained ~1% but diverged post-timing (as did
// R12's gather widening) — structural micro-edits to proven kernels have
// negative risk-adjusted value here. Banking the stable configuration:
// - transform-then-gather reformulation (gather = 1 load/edge, no branches)
// - fragment-linear BTf in LDS (B never re-read from L2 per wave)
// - int8 xw1 (64B rows = 1 line/edge on gather-1; exact int32 accumulation)
// - xw2 stays bf16 (logit span ~±60 vs threshold 2.52 rules out int8)

typedef __attribute__((ext_vector_type(8))) short short8;
typedef __attribute__((ext_vector_type(4))) float floatx4;

static __device__ __forceinline__ unsigned short f2bf(float f) {
    unsigned u = __float_as_uint(f);
    u += 0x7FFFu + ((u >> 16) & 1u);      // RNE
    return (unsigned short)(u >> 16);
}
static __device__ __forceinline__ float bflo(unsigned u) { return __uint_as_float(u << 16); }
static __device__ __forceinline__ float bfhi(unsigned u) { return __uint_as_float(u & 0xffff0000u); }

// sigma: within-slab col interleave, involution on [0,64)
static __device__ __forceinline__ int sgm(int d) {
    return ((d & 12) << 2) | ((d & 48) >> 2) | (d & 3);
}

// ---- pack weights into fragment-linear BTf (bf16; MFMA operands) ----
// chunk = (cb*2+k0)*4+g (1KB each); within chunk, lane=lg*16+lr holds 8 shorts:
//   BTf[chunk*512 + lg*128 + lr*8 + s] = B[cb*64+g*16+lr][k0*32+lg*8+s]
// Layer1: B[j][d] = W1[r][d][f], j=r*64+f.       (8 slabs, 32768 shorts)
// Layer2: B[j][d] = W2[r][sgm(d)][f], j=r*40+f.  (5 slabs, 20480 shorts)
__global__ void k_packw(const float* __restrict__ W1, const float* __restrict__ W2,
                        unsigned short* __restrict__ BTf1, unsigned short* __restrict__ BTf2) {
    int i = blockIdx.x * 256 + threadIdx.x;
    if (i < 32768) {
        int chunk = i >> 9, w = i & 511;
        int cb = chunk >> 3, k0 = (chunk >> 2) & 1, g = chunk & 3;
        int lg = w >> 7, lr = (w >> 3) & 15, s = w & 7;
        int j = cb * 64 + g * 16 + lr;
        int d = k0 * 32 + lg * 8 + s;
        int r = j >> 6, f = j & 63;
        BTf1[i] = f2bf(W1[r * 4096 + d * 64 + f]);
    } else if (i < 32768 + 20480) {
        int ii = i - 32768;
        int chunk = ii >> 9, w = ii & 511;
        int cb = chunk >> 3, k0 = (chunk >> 2) & 1, g = chunk & 3;
        int lg = w >> 7, lr = (w >> 3) & 15, s = w & 7;
        int j = cb * 64 + g * 16 + lr;                 // < 320
        int d = k0 * 32 + lg * 8 + s;
        int r = j / 40, f = j - r * 40;
        BTf2[ii] = f2bf(W2[r * 2560 + sgm(d) * 40 + f]);
    }
}

// ---- layer-1 GEMM: xw1[MP][512B] = int8( cast(x) @ W1^T · 16 )  (B in LDS) ----
// sigma-phys int8 output: row n, slab cb, phys col lg*16+g*4+i -> byte
// n*512 + cb*64 + lg*16 + g*4 + i; one 16B store per slab per thread.
__global__ __launch_bounds__(256) void k_xw1(
    const float* __restrict__ Af, const unsigned short* __restrict__ BTf,
    char* __restrict__ xw, int M) {
    __shared__ short Bs[8 * 4096];            // 64KB
#pragma unroll
    for (int off = 0; off < 8 * 4096; off += 2048)
        *(short8*)(Bs + off + threadIdx.x * 8) =
            *(const short8*)((const short*)BTf + off + threadIdx.x * 8);

    int wave = threadIdx.x >> 6, lane = threadIdx.x & 63;
    int lr = lane & 15, lg = lane >> 4;
    int rowbase = (blockIdx.x * 4 + wave) * 16;
    int row = rowbase + lr;

    short8 af[2];                             // fused f32->bf16 cast, read once
#pragma unroll
    for (int k0 = 0; k0 < 2; ++k0) {
        int koff = k0 * 32 + lg * 8;
        float4 v0 = {0, 0, 0, 0}, v1 = {0, 0, 0, 0};
        if (row < M) {
            v0 = *(const float4*)(Af + (size_t)row * 64 + koff);
            v1 = *(const float4*)(Af + (size_t)row * 64 + koff + 4);
        }
        short8 t;
        t[0] = (short)f2bf(v0.x); t[1] = (short)f2bf(v0.y);
        t[2] = (short)f2bf(v0.z); t[3] = (short)f2bf(v0.w);
        t[4] = (short)f2bf(v1.x); t[5] = (short)f2bf(v1.y);
        t[6] = (short)f2bf(v1.z); t[7] = (short)f2bf(v1.w);
        af[k0] = t;
    }

    __syncthreads();                          // LDS B ready

#pragma unroll
    for (int cb = 0; cb < 8; ++cb) {
        floatx4 acc[4] = {};
#pragma unroll
        for (int k0 = 0; k0 < 2; ++k0)
#pragma unroll
            for (int g = 0; g < 4; ++g) {
                short8 b = *(const short8*)(Bs + ((cb * 2 + k0) * 4 + g) * 512 + lane * 8);
                acc[g] = __builtin_amdgcn_mfma_f32_16x16x32_bf16(b, af[k0], acc[g], 0, 0, 0);
            }
        // quantize 16 values to int8 (scale 16, RNE, clamp) and pack 16B
        unsigned dw[4];
#pragma unroll
        for (int g = 0; g < 4; ++g) {
            unsigned d = 0;
#pragma unroll
            for (int i = 0; i < 4; ++i) {
                int q = (int)rintf(acc[g][i] * 16.0f);
                q = q > 127 ? 127 : (q < -127 ? -127 : q);
                d |= ((unsigned)q & 255u) << (8 * i);
            }
            dw[g] = d;
        }
        int4 o = {(int)dw[0], (int)dw[1], (int)dw[2], (int)dw[3]};
        *(int4*)(xw + (size_t)row * 512 + cb * 64 + lg * 16) = o;
    }
}

// ---- gather-sum(int8) + relu -> h bf16 [MP][64] (phys layout); zero pad rows ----
// 2 rows/wave (proven shape): half-wave eo owns one row; lane loads ushort
// (2 int8 feats); exact int32 accumulation; one scale+relu at the end.
__global__ __launch_bounds__(256) void k_gs_relu(
    const char* __restrict__ xw,             // [(n*8+r)][64B] int8 (scale 1/16)
    const int* __restrict__ ptr, const int* __restrict__ idx,
    const int* __restrict__ rel,
    unsigned short* __restrict__ H, int M, int MP) {
    int rowA = (blockIdx.x * 4 + (threadIdx.x >> 6)) * 2;
    if (rowA >= MP) return;
    rowA = __builtin_amdgcn_readfirstlane(rowA);
    int lane = threadIdx.x & 63;
    int fl = lane & 31, eo = lane >> 5;
    int rowB = rowA + 1;
    int myrow = eo ? rowB : rowA;
    if (rowA >= M) {                          // pad pair -> zeros
        *(unsigned*)(H + (size_t)myrow * 64 + fl * 2) = 0;
        return;
    }
    int ix = 0, iy = 0;
    bool both = (rowB < M);
    int p0 = ptr[rowA], p1 = ptr[rowA + 1];
    int p2 = both ? ptr[rowA + 2] : p1;
    if (both && (p1 - p0 == 16) && (p2 - p1 == 16)) {
        const int* ia = idx + p0; const int* ra_ = rel + p0;   // scalar (uniform)
        const int* ib = idx + p1; const int* rb_ = rel + p1;
        unsigned short u[16];
#pragma unroll
        for (int t = 0; t < 16; ++t) {
            unsigned bA = ((unsigned)ia[t] * 8u + (unsigned)ra_[t]) * 64u;
            unsigned bB = ((unsigned)ib[t] * 8u + (unsigned)rb_[t]) * 64u;
            unsigned b = eo ? bB : bA;
            u[t] = *(const unsigned short*)(xw + b + fl * 2);
        }
#pragma unroll
        for (int t = 0; t < 16; ++t) {
            ix += (int)(signed char)(u[t] & 0xff);
            iy += (int)(signed char)(u[t] >> 8);
        }
    } else {
        int ps = 0, deg = 0;
        if (myrow < M) { ps = ptr[myrow]; deg = ptr[myrow + 1] - ps; }
        for (int t = 0; t < deg; ++t) {
            unsigned b = ((unsigned)idx[ps + t] * 8u + (unsigned)rel[ps + t]) * 64u;
            unsigned short u = *(const unsigned short*)(xw + b + fl * 2);
            ix += (int)(signed char)(u & 0xff);
            iy += (int)(signed char)(u >> 8);
        }
    }
    float cx = (float)ix * 0.0625f, cy = (float)iy * 0.0625f;
    unsigned o = ((unsigned)f2bf(fmaxf(cy, 0.f)) << 16) | f2bf(fmaxf(cx, 0.f));
    *(unsigned*)(H + (size_t)myrow * 64 + fl * 2) = o;
}

// ---- layer-2 GEMM: xw2[MP][320] = h @ W2^T  (bf16, B in LDS, logical cols) ----
__global__ __launch_bounds__(256) void k_xw2(
    const unsigned short* __restrict__ Ab, const unsigned short* __restrict__ BTf,
    unsigned short* __restrict__ xw, int M) {
    __shared__ short Bs[5 * 4096];            // 40KB
#pragma unroll
    for (int off = 0; off < 5 * 4096; off += 2048)
        *(short8*)(Bs + off + threadIdx.x * 8) =
            *(const short8*)((const short*)BTf + off + threadIdx.x * 8);

    int wave = threadIdx.x >> 6, lane = threadIdx.x & 63;
    int lr = lane & 15, lg = lane >> 4;
    int rowbase = (blockIdx.x * 4 + wave) * 16;
    int row = rowbase + lr;

    short8 af[2];
#pragma unroll
    for (int k0 = 0; k0 < 2; ++k0)
        af[k0] = *(const short8*)(Ab + (size_t)row * 64 + k0 * 32 + lg * 8);

    __syncthreads();

#pragma unroll
    for (int cb = 0; cb < 5; ++cb) {
        int col0 = cb * 64;
        floatx4 acc[4] = {};
#pragma unroll
        for (int k0 = 0; k0 < 2; ++k0)
#pragma unroll
            for (int g = 0; g < 4; ++g) {
                short8 b = *(const short8*)(Bs + ((cb * 2 + k0) * 4 + g) * 512 + lane * 8);
                acc[g] = __builtin_amdgcn_mfma_f32_16x16x32_bf16(b, af[k0], acc[g], 0, 0, 0);
            }
        // logical store: acc[g][i] = col col0 + g*16 + lg*4 + i of row
#pragma unroll
        for (int g = 0; g < 4; ++g) {
            unsigned lo = ((unsigned)f2bf(acc[g][1]) << 16) | f2bf(acc[g][0]);
            unsigned hi = ((unsigned)f2bf(acc[g][3]) << 16) | f2bf(acc[g][2]);
            uint2 o = {lo, hi};
            *(uint2*)(xw + (size_t)row * 320 + col0 + g * 16 + lg * 4) = o;
        }
    }
}

// ---- gather-sum + log_softmax -> out f32 [M][40]  (xw2 bf16 logical) ----
__global__ __launch_bounds__(256) void k_gs_lsm(
    const unsigned short* __restrict__ xw,   // [(n*8+r)][40] logical
    const int* __restrict__ ptr, const int* __restrict__ idx,
    const int* __restrict__ rel,
    float* __restrict__ out, int M) {
    int rowA = (blockIdx.x * 4 + (threadIdx.x >> 6)) * 2;
    if (rowA >= M) return;
    rowA = __builtin_amdgcn_readfirstlane(rowA);
    int lane = threadIdx.x & 63;
    int fl = lane & 31, eo = lane >> 5;
    int rowB = rowA + 1;
    int myrow = eo ? rowB : rowA;
    bool okf = fl < 20;
    int flc = okf ? fl : 0;
    float cx = 0.f, cy = 0.f;
    bool both = (rowB < M);
    int p0 = ptr[rowA], p1 = ptr[rowA + 1];
    int p2 = both ? ptr[rowA + 2] : p1;
    if (both && (p1 - p0 == 16) && (p2 - p1 == 16)) {
        const int* ia = idx + p0; const int* ra_ = rel + p0;
        const int* ib = idx + p1; const int* rb_ = rel + p1;
        unsigned u[16];
#pragma unroll
        for (int t = 0; t < 16; ++t) {
            unsigned bA = ((unsigned)ia[t] * 8u + (unsigned)ra_[t]) * 80u;
            unsigned bB = ((unsigned)ib[t] * 8u + (unsigned)rb_[t]) * 80u;
            unsigned b = eo ? bB : bA;
            u[t] = *(const unsigned*)((const char*)xw + b + flc * 4);
        }
#pragma unroll
        for (int t = 0; t < 16; ++t) { cx += bflo(u[t]); cy += bfhi(u[t]); }
    } else {
        int ps = 0, deg = 0;
        if (myrow < M) { ps = ptr[myrow]; deg = ptr[myrow + 1] - ps; }
        for (int t = 0; t < deg; ++t) {
            unsigned b = ((unsigned)idx[ps + t] * 8u + (unsigned)rel[ps + t]) * 80u;
            unsigned u = *(const unsigned*)((const char*)xw + b + flc * 4);
            cx += bflo(u); cy += bfhi(u);
        }
    }
    float mx = okf ? fmaxf(cx, cy) : -INFINITY;
#pragma unroll
    for (int m = 1; m < 32; m <<= 1) mx = fmaxf(mx, __shfl_xor(mx, m, 32));
    float s = okf ? (__expf(cx - mx) + __expf(cy - mx)) : 0.f;
#pragma unroll
    for (int m = 1; m < 32; m <<= 1) s += __shfl_xor(s, m, 32);
    float lse = mx + __logf(s);
    if (okf && myrow < M) {
        float2 o = {cx - lse, cy - lse};
        *(float2*)(out + (size_t)myrow * 40 + flc * 2) = o;
    }
}

extern "C" void kernel_launch(void* const* d_in, const int* in_sizes, int n_in,
                              void* d_out, int out_size, void* d_ws, size_t ws_size,
                              hipStream_t stream) {
    const float* x  = (const float*)d_in[0];
    const int* ptr  = (const int*)d_in[1];
    const int* idx  = (const int*)d_in[2];
    const int* rel  = (const int*)d_in[3];
    const float* W1 = (const float*)d_in[4];
    const float* W2 = (const float*)d_in[5];
    float* out = (float*)d_out;

    int N = in_sizes[1] - 1;                 // 75000
    int MP = (N + 255) & ~255;               // 75008

    char* ws = (char*)d_ws;
    unsigned short* BTf1 = (unsigned short*)ws;
    unsigned short* BTf2 = BTf1 + 32768;
    unsigned short* hbf  = BTf2 + 20480;                    // [MP][64] bf16 = 9.6MB
    char*           xw1b = (char*)(hbf + (size_t)MP * 64);  // [MP][512] int8 = 38.4MB
    unsigned short* xw2b = (unsigned short*)(xw1b + (size_t)MP * 512);  // [MP][320] bf16 = 48MB
    // total ws use ~= 96.2MB; all regions disjoint

    k_packw<<<(32768 + 20480 + 255) / 256, 256, 0, stream>>>(W1, W2, BTf1, BTf2);

    int nblk = MP / 64;                      // 1172 blocks: 4 waves x 16 rows
    // layer 1: xw1 = int8(cast(x) @ W1, scale 16) (8 slabs, sigma-phys, B in 64KB LDS)
    k_xw1<<<nblk, 256, 0, stream>>>(x, BTf1, xw1b, N);
    k_gs_relu<<<MP / 8, 256, 0, stream>>>(xw1b, ptr, idx, rel, hbf, N, MP);
    // layer 2: xw2 = h @ W2 (bf16, 5 slabs, logical cols, B in 40KB LDS)
    k_xw2<<<nblk, 256, 0, stream>>>(hbf, BTf2, xw2b, MP);
    k_gs_lsm<<<(N + 7) / 8, 256, 0, stream>>>(xw2b, ptr, idx, rel, out, N);
}